// Round 1
// baseline (239.146 us; speedup 1.0000x reference)
//
#include <hip/hip_runtime.h>
#include <math.h>

// Problem constants (fixed by setup_inputs)
#define NB 16
#define NT 4096
#define NC 64
#define NS 5
#define NH 32

#define TTILE 64
#define RMX 56
#define PN (TTILE + 2*RMX)   // 176 staged t-positions per tile

// tap table segment offsets: radii {10,16,24,36,56} -> lengths {21,33,49,73,113}
#define OFF0 0
#define OFF1 21
#define OFF2 54
#define OFF3 103
#define OFF4 176
#define NTAPS 289

// ---------------- init: normalized Gaussian taps into d_ws ----------------
__global__ void init_taps_kernel(float* __restrict__ ws) {
    __shared__ float raw[NTAPS];
    __shared__ float invs[NS];
    const int offs[6] = {OFF0, OFF1, OFF2, OFF3, OFF4, NTAPS};
    const float sig[NS] = {2.5f, 4.0f, 6.0f, 9.0f, 14.0f};
    const int RR[NS] = {10, 16, 24, 36, 56};
    const int tid = threadIdx.x;
    for (int i = tid; i < NTAPS; i += blockDim.x) {
        int s = 0;
        #pragma unroll
        for (int k = 1; k < NS; ++k) if (i >= offs[k]) s = k;
        const int j = i - offs[s] - RR[s];
        const float u = (float)j / sig[s];
        raw[i] = expf(-0.5f * u * u);
    }
    __syncthreads();
    if (tid < NS) {
        float sum = 0.f;
        for (int i = offs[tid]; i < offs[tid + 1]; ++i) sum += raw[i];
        invs[tid] = 1.0f / (sum + 1e-12f);
    }
    __syncthreads();
    for (int i = tid; i < NTAPS; i += blockDim.x) {
        int s = 0;
        #pragma unroll
        for (int k = 1; k < NS; ++k) if (i >= offs[k]) s = k;
        ws[i] = raw[i] * invs[s];
    }
}

// ---------------- helpers ----------------
// Abramowitz-Stegun 7.1.26, |err| <= 1.5e-7, branchless.
__device__ __forceinline__ float fast_erf(float x) {
    const float ax = fabsf(x);
    const float t = __fdividef(1.0f, fmaf(0.3275911f, ax, 1.0f));
    float p = fmaf(t, 1.061405429f, -1.453152027f);
    p = fmaf(t, p, 1.421413741f);
    p = fmaf(t, p, -0.284496736f);
    p = fmaf(t, p, 0.254829592f);
    p *= t;
    const float e = __expf(-ax * ax);
    const float r = fmaf(-p, e, 1.0f);
    return copysignf(r, x);
}

__device__ __forceinline__ float gelu_exact(float a) {
    return 0.5f * a * (1.0f + fast_erf(a * 0.70710678118654752f));
}

// ---------------- fused main kernel ----------------
// grid: NB * (NT/TTILE) blocks, 256 threads.
// block -> (b, t-tile). wave w handles t rows [16w,16w+16), lane = channel.
__global__ __launch_bounds__(256) void fused_kernel(
    const float* __restrict__ x,  const float* __restrict__ W1,
    const float* __restrict__ b1, const float* __restrict__ W2,
    const float* __restrict__ b2, const float* __restrict__ taps,
    float* __restrict__ out)
{
    __shared__ float sx[PN * NC];   // 45056 B

    const int blk = blockIdx.x;
    const int b  = blk >> 6;              // NT/TTILE = 64
    const int t0 = (blk & 63) * TTILE;
    const float* xb = x + (size_t)b * NT * NC;
    const int tid = threadIdx.x;

    // stage x[t0-56 .. t0+119][0..63] with reflect padding, float4 loads
    for (int idx = tid; idx < PN * 16; idx += 256) {
        const int p  = idx >> 4;
        const int c4 = (idx & 15) << 2;
        int g = t0 - RMX + p;
        if (g < 0) g = -g;                 // np.pad 'reflect'
        if (g >= NT) g = 2 * NT - 2 - g;
        const float4 v = *reinterpret_cast<const float4*>(xb + (size_t)g * NC + c4);
        *reinterpret_cast<float4*>(&sx[p * NC + c4]) = v;
    }
    __syncthreads();

    const int lane = tid & 63;
    const int wave = tid >> 6;
    const int toff = wave << 4;           // wave's first t (tile-local)
    const float* xs = sx + lane;          // stride-64 reads: conflict-free

    for (int grp = 0; grp < 4; ++grp) {
        const int tg = toff + (grp << 2); // first of 4 output t's (tile-local)

        // ---------------- conv: 5 sigmas x 4 outputs ----------------
        float acc[NS][4];
        #pragma unroll
        for (int s = 0; s < NS; ++s)
            #pragma unroll
            for (int d = 0; d < 4; ++d) acc[s][d] = 0.f;

        // sliding window: w0..w3 = x_ext[tg + j + 0..3]; LDS p = i + RMX
        float w0 = xs[(tg + 0) * NC];
        float w1 = xs[(tg + 1) * NC];
        float w2 = xs[(tg + 2) * NC];
        float w3 = xs[(tg + 3) * NC];
        #pragma unroll
        for (int j = -RMX; j <= RMX; ++j) {
            const int aj = j < 0 ? -j : j;
            if (aj <= 10) {
                const float wt = taps[OFF0 + j + 10];
                acc[0][0] = fmaf(wt, w0, acc[0][0]);
                acc[0][1] = fmaf(wt, w1, acc[0][1]);
                acc[0][2] = fmaf(wt, w2, acc[0][2]);
                acc[0][3] = fmaf(wt, w3, acc[0][3]);
            }
            if (aj <= 16) {
                const float wt = taps[OFF1 + j + 16];
                acc[1][0] = fmaf(wt, w0, acc[1][0]);
                acc[1][1] = fmaf(wt, w1, acc[1][1]);
                acc[1][2] = fmaf(wt, w2, acc[1][2]);
                acc[1][3] = fmaf(wt, w3, acc[1][3]);
            }
            if (aj <= 24) {
                const float wt = taps[OFF2 + j + 24];
                acc[2][0] = fmaf(wt, w0, acc[2][0]);
                acc[2][1] = fmaf(wt, w1, acc[2][1]);
                acc[2][2] = fmaf(wt, w2, acc[2][2]);
                acc[2][3] = fmaf(wt, w3, acc[2][3]);
            }
            if (aj <= 36) {
                const float wt = taps[OFF3 + j + 36];
                acc[3][0] = fmaf(wt, w0, acc[3][0]);
                acc[3][1] = fmaf(wt, w1, acc[3][1]);
                acc[3][2] = fmaf(wt, w2, acc[3][2]);
                acc[3][3] = fmaf(wt, w3, acc[3][3]);
            }
            {
                const float wt = taps[OFF4 + j + 56];
                acc[4][0] = fmaf(wt, w0, acc[4][0]);
                acc[4][1] = fmaf(wt, w1, acc[4][1]);
                acc[4][2] = fmaf(wt, w2, acc[4][2]);
                acc[4][3] = fmaf(wt, w3, acc[4][3]);
            }
            if (j < RMX) {
                w0 = w1; w1 = w2; w2 = w3;
                w3 = xs[(tg + j + 4 + RMX) * NC];
            }
        }

        // ---------------- causal stats (win=16, replicate-left, /eff) ----------------
        // window values x[clamp(t-15..t, >=0)] for t = tg..tg+3  -> 19 loads
        float xw[19];
        #pragma unroll
        for (int q = 0; q < 19; ++q) {
            const int gidx = t0 + tg - 15 + q;
            const int gc = gidx < 0 ? 0 : gidx;     // replicate pad
            xw[q] = xs[(gc - t0 + RMX) * NC];
        }
        float s1 = 0.f, s2 = 0.f;
        #pragma unroll
        for (int q = 0; q < 16; ++q) { const float v = xw[q]; s1 += v; s2 = fmaf(v, v, s2); }

        #pragma unroll
        for (int d = 0; d < 4; ++d) {
            const int tglob = t0 + tg + d;
            const float eff = fminf((float)(tglob + 1), 16.0f);
            const float re = __fdividef(1.0f, eff + 1e-12f);
            const float mn = s1 * re;
            const float m2 = s2 * re;
            const float var = fmaxf(m2 - mn * mn, 0.f);
            const float xt = xw[15 + d];
            const float z = (xt - mn) * rsqrtf(var + 1e-6f);
            const float lv = __logf(var + 1e-6f);

            // MLP: 2 -> 32 (exact GELU) -> 5 ; weights via wave-uniform s_loads
            float l0 = b2[0], l1 = b2[1], l2 = b2[2], l3 = b2[3], l4 = b2[4];
            for (int j = 0; j < NH; ++j) {
                const float a = fmaf(z, W1[2 * j], fmaf(lv, W1[2 * j + 1], b1[j]));
                const float g = gelu_exact(a);
                l0 = fmaf(g, W2[j],            l0);
                l1 = fmaf(g, W2[NH + j],       l1);
                l2 = fmaf(g, W2[2 * NH + j],   l2);
                l3 = fmaf(g, W2[3 * NH + j],   l3);
                l4 = fmaf(g, W2[4 * NH + j],   l4);
            }

            // softmax(logits / 0.7) and weighted sum of the 5 smoothed values
            const float sc = 1.4285714285714286f;  // 1/0.7
            const float mx = fmaxf(fmaxf(fmaxf(l0, l1), fmaxf(l2, l3)), l4);
            const float e0 = __expf((l0 - mx) * sc);
            const float e1 = __expf((l1 - mx) * sc);
            const float e2 = __expf((l2 - mx) * sc);
            const float e3 = __expf((l3 - mx) * sc);
            const float e4 = __expf((l4 - mx) * sc);
            const float den = e0 + e1 + e2 + e3 + e4;
            const float num = e0 * acc[0][d] + e1 * acc[1][d] + e2 * acc[2][d]
                            + e3 * acc[3][d] + e4 * acc[4][d];
            out[((size_t)b * NT + tglob) * NC + lane] = __fdividef(num, den);

            if (d < 3) {   // slide the 16-window by one
                const float ad = xw[16 + d], sb = xw[d];
                s1 += ad - sb;
                s2 += ad * ad - sb * sb;
            }
        }
    }
}

extern "C" void kernel_launch(void* const* d_in, const int* in_sizes, int n_in,
                              void* d_out, int out_size, void* d_ws, size_t ws_size,
                              hipStream_t stream) {
    const float* x  = (const float*)d_in[0];
    const float* W1 = (const float*)d_in[1];
    const float* b1 = (const float*)d_in[2];
    const float* W2 = (const float*)d_in[3];
    const float* b2 = (const float*)d_in[4];
    float* out = (float*)d_out;
    float* taps = (float*)d_ws;

    init_taps_kernel<<<1, 320, 0, stream>>>(taps);
    fused_kernel<<<NB * (NT / TTILE), 256, 0, stream>>>(x, W1, b1, W2, b2, taps, out);
}

// Round 2
// 134.886 us; speedup vs baseline: 1.7730x; 1.7730x over previous
//
#include <hip/hip_runtime.h>
#include <math.h>

// Problem constants (fixed by setup_inputs)
#define NB 16
#define NT 4096
#define NC 64
#define NS 5
#define NH 32

#define TTILE 64
#define RMX 56
#define PN (TTILE + 2*RMX)   // 176 staged t-positions per tile

// tap table segment offsets: radii {10,16,24,36,56} -> lengths {21,33,49,73,113}
#define OFF0 0
#define OFF1 21
#define OFF2 54
#define OFF3 103
#define OFF4 176
#define NTAPS 289

#define NFRAG 13            // K-steps total: 2+2+2+3+4
#define SXT_LD 184          // bf16 elements per channel row (16B-aligned, bank-balanced)
#define SXS_LD 67           // f32 stride for stats array (bank-friendly)
#define SN 79               // stats rows: t0-15 .. t0+63

typedef __attribute__((ext_vector_type(8))) short bf16x8;
typedef __attribute__((ext_vector_type(4))) float f32x4;

__device__ __forceinline__ unsigned short f2b(float f) {
    unsigned int u = __float_as_uint(f);
    unsigned int r = (u + 0x7fffu + ((u >> 16) & 1u)) >> 16;   // RNE
    return (unsigned short)r;
}

// ---------------- init: normalized taps -> MFMA A-fragments in d_ws ----------------
// frag f in [0,13): (sigma s, kstep kk). Layout: afr[(f*64 + lane)*8 + e] (bf16 as u16).
// A[r][k] = tap_s(32*kk + k - RA[s] - r), r = lane&15, k = 8*(lane>>4)+e.
__global__ void init_frags_kernel(unsigned short* __restrict__ afr) {
    __shared__ float raw[NTAPS];
    __shared__ float invs[NS];
    const int offs[6] = {OFF0, OFF1, OFF2, OFF3, OFF4, NTAPS};
    const float sig[NS] = {2.5f, 4.0f, 6.0f, 9.0f, 14.0f};
    const int RR[NS] = {10, 16, 24, 36, 56};
    const int tid = threadIdx.x;
    for (int i = tid; i < NTAPS; i += blockDim.x) {
        int s = 0;
        #pragma unroll
        for (int k = 1; k < NS; ++k) if (i >= offs[k]) s = k;
        const int j = i - offs[s] - RR[s];
        const float u = (float)j / sig[s];
        raw[i] = expf(-0.5f * u * u);
    }
    __syncthreads();
    if (tid < NS) {
        float sum = 0.f;
        for (int i = offs[tid]; i < offs[tid + 1]; ++i) sum += raw[i];
        invs[tid] = 1.0f / (sum + 1e-12f);
    }
    __syncthreads();
    const int fbase6[6] = {0, 2, 4, 6, 9, 13};
    const int RA[NS] = {16, 16, 24, 40, 56};
    for (int idx = tid; idx < NFRAG * 64 * 8; idx += blockDim.x) {
        const int f = idx >> 9;
        const int lane = (idx >> 3) & 63;
        const int e = idx & 7;
        int s = 0;
        #pragma unroll
        for (int k = 1; k < NS; ++k) if (f >= fbase6[k]) s = k;
        const int kk = f - fbase6[s];
        const int r = lane & 15;
        const int g = lane >> 4;
        const int j = 32 * kk + 8 * g + e - RA[s] - r;
        float v = 0.f;
        if (j >= -RR[s] && j <= RR[s]) v = raw[offs[s] + j + RR[s]] * invs[s];
        afr[idx] = f2b(v);
    }
}

// ---------------- fused main kernel ----------------
// grid: NB * (NT/TTILE) blocks, 256 threads. Wave w owns t-rows [16w,16w+16).
// Conv on MFMA (A=taps frags, B=x from transposed bf16 LDS); stats+MLP on VALU.
__global__ __launch_bounds__(256, 3) void fused2_kernel(
    const float* __restrict__ x,  const float* __restrict__ W1,
    const float* __restrict__ b1, const float* __restrict__ W2,
    const float* __restrict__ b2, const unsigned short* __restrict__ afr,
    float* __restrict__ out)
{
    __shared__ __align__(16) short sxT[64 * SXT_LD];   // bf16 [c][t], 23552 B
    __shared__ __align__(16) float sxS[SN * SXS_LD];   // f32 [row][c], 21172 B
    __shared__ __align__(16) float wpk[NH * 8];        // per-j packed weights, 1024 B

    const int blk = blockIdx.x;
    const int b  = blk >> 6;              // NT/TTILE = 64
    const int t0 = (blk & 63) * TTILE;
    const float* xb = x + (size_t)b * NT * NC;
    const int tid = threadIdx.x;

    // pack weights: wpk[j][0..7] = {W1[2j], W1[2j+1], b1[j], W2[0][j..4][j]}
    {
        const int j = tid >> 3, q = tid & 7;
        float v;
        if (q < 2)       v = W1[2 * j + q];
        else if (q == 2) v = b1[j];
        else             v = W2[(q - 3) * NH + j];
        wpk[tid] = v;
    }
    // stage sxT (bf16, transposed, reflect-padded)
    for (int idx = tid; idx < PN * 16; idx += 256) {
        const int p = idx >> 4, c4 = (idx & 15) << 2;
        int gg = t0 - RMX + p;
        if (gg < 0) gg = -gg;
        if (gg >= NT) gg = 2 * NT - 2 - gg;
        const float4 v = *reinterpret_cast<const float4*>(xb + (size_t)gg * NC + c4);
        sxT[(c4 + 0) * SXT_LD + p] = (short)f2b(v.x);
        sxT[(c4 + 1) * SXT_LD + p] = (short)f2b(v.y);
        sxT[(c4 + 2) * SXT_LD + p] = (short)f2b(v.z);
        sxT[(c4 + 3) * SXT_LD + p] = (short)f2b(v.w);
    }
    // stage sxS (f32, replicate-left for causal stats)
    for (int idx = tid; idx < SN * 16; idx += 256) {
        const int i = idx >> 4, c4 = (idx & 15) << 2;
        int gg = t0 - 15 + i; if (gg < 0) gg = 0;
        const float4 v = *reinterpret_cast<const float4*>(xb + (size_t)gg * NC + c4);
        float* dst = &sxS[i * SXS_LD + c4];
        dst[0] = v.x; dst[1] = v.y; dst[2] = v.z; dst[3] = v.w;
    }
    __syncthreads();

    const int lane = tid & 63, w = tid >> 6;
    const int i16 = lane & 15, g = lane >> 4;

    const int fbase[NS] = {0, 2, 4, 6, 9};
    const int ksn[NS]   = {2, 2, 2, 3, 4};
    const int RA[NS]    = {16, 16, 24, 40, 56};

    const float bb0 = b2[0], bb1 = b2[1], bb2v = b2[2], bb3 = b2[3], bb4 = b2[4];

    #pragma unroll
    for (int ct = 0; ct < 4; ++ct) {
        const int c = 16 * ct + i16;

        // ---- conv via MFMA: 13 k-steps over 5 sigmas ----
        f32x4 acc[NS];
        #pragma unroll
        for (int s = 0; s < NS; ++s) acc[s] = (f32x4){0.f, 0.f, 0.f, 0.f};
        #pragma unroll
        for (int s = 0; s < NS; ++s) {
            #pragma unroll
            for (int kk = 0; kk < ksn[s]; ++kk) {
                const bf16x8 A = *reinterpret_cast<const bf16x8*>(
                    afr + ((size_t)(fbase[s] + kk) * 64 + lane) * 8);
                const int tof = 16 * w - RA[s] + 32 * kk + RMX + 8 * g;
                const bf16x8 B = *reinterpret_cast<const bf16x8*>(&sxT[c * SXT_LD + tof]);
                acc[s] = __builtin_amdgcn_mfma_f32_16x16x32_bf16(A, B, acc[s], 0, 0, 0);
            }
        }

        // ---- causal stats for this lane's 4 t's (t = t0+16w+4g+d) ----
        const int i0 = 16 * w + 4 * g;
        float xw[19];
        #pragma unroll
        for (int q = 0; q < 19; ++q) xw[q] = sxS[(i0 + q) * SXS_LD + c];
        float s1 = 0.f, s2 = 0.f;
        #pragma unroll
        for (int q = 0; q < 16; ++q) { const float v = xw[q]; s1 += v; s2 = fmaf(v, v, s2); }
        float zf[4], lvf[4];
        #pragma unroll
        for (int d = 0; d < 4; ++d) {
            const int tglob = t0 + 16 * w + 4 * g + d;
            const float eff = fminf((float)(tglob + 1), 16.0f);
            const float re = __fdividef(1.0f, eff + 1e-12f);
            const float mn = s1 * re;
            const float m2 = s2 * re;
            const float var = fmaxf(m2 - mn * mn, 0.f);
            zf[d] = (xw[15 + d] - mn) * rsqrtf(var + 1e-6f);
            lvf[d] = __logf(var + 1e-6f);
            if (d < 3) {
                const float ad = xw[16 + d], sb = xw[d];
                s1 += ad - sb;
                s2 += ad * ad - sb * sb;
            }
        }

        // ---- MLP, 4 outputs in flight ----
        float l0[4], l1[4], l2[4], l3[4], l4[4];
        #pragma unroll
        for (int d = 0; d < 4; ++d) { l0[d]=bb0; l1[d]=bb1; l2[d]=bb2v; l3[d]=bb3; l4[d]=bb4; }
        #pragma unroll 4
        for (int j = 0; j < NH; ++j) {
            const float4 wa = *reinterpret_cast<const float4*>(&wpk[j * 8]);
            const float4 wb = *reinterpret_cast<const float4*>(&wpk[j * 8 + 4]);
            #pragma unroll
            for (int d = 0; d < 4; ++d) {
                const float a  = fmaf(zf[d], wa.x, fmaf(lvf[d], wa.y, wa.z));
                const float ha = 0.5f * a;
                const float au = fabsf(a) * 0.70710678118654752f;
                const float t  = __fdividef(1.0f, fmaf(0.3275911f, au, 1.0f));
                float p = fmaf(t, 1.061405429f, -1.453152027f);
                p = fmaf(t, p, 1.421413741f);
                p = fmaf(t, p, -0.284496736f);
                p = fmaf(t, p, 0.254829592f);
                p *= t;
                const float e = __expf(-au * au);
                float er = fmaf(-p, e, 1.0f);
                er = copysignf(er, a);
                const float gl = fmaf(ha, er, ha);   // gelu
                l0[d] = fmaf(gl, wa.w, l0[d]);
                l1[d] = fmaf(gl, wb.x, l1[d]);
                l2[d] = fmaf(gl, wb.y, l2[d]);
                l3[d] = fmaf(gl, wb.z, l3[d]);
                l4[d] = fmaf(gl, wb.w, l4[d]);
            }
        }

        // ---- softmax + weighted sum + store ----
        #pragma unroll
        for (int d = 0; d < 4; ++d) {
            const float sc = 1.4285714285714286f;  // 1/0.7
            const float mx = fmaxf(fmaxf(fmaxf(l0[d], l1[d]), fmaxf(l2[d], l3[d])), l4[d]);
            const float e0 = __expf((l0[d] - mx) * sc);
            const float e1 = __expf((l1[d] - mx) * sc);
            const float e2 = __expf((l2[d] - mx) * sc);
            const float e3 = __expf((l3[d] - mx) * sc);
            const float e4 = __expf((l4[d] - mx) * sc);
            const float den = e0 + e1 + e2 + e3 + e4;
            const float num = e0 * acc[0][d] + e1 * acc[1][d] + e2 * acc[2][d]
                            + e3 * acc[3][d] + e4 * acc[4][d];
            const int tglob = t0 + 16 * w + 4 * g + d;
            out[((size_t)b * NT + tglob) * NC + c] = __fdividef(num, den);
        }
    }
}

extern "C" void kernel_launch(void* const* d_in, const int* in_sizes, int n_in,
                              void* d_out, int out_size, void* d_ws, size_t ws_size,
                              hipStream_t stream) {
    const float* x  = (const float*)d_in[0];
    const float* W1 = (const float*)d_in[1];
    const float* b1 = (const float*)d_in[2];
    const float* W2 = (const float*)d_in[3];
    const float* b2 = (const float*)d_in[4];
    float* out = (float*)d_out;
    unsigned short* afr = (unsigned short*)d_ws;   // 13*64*8 u16 = 13312 B

    init_frags_kernel<<<1, 256, 0, stream>>>(afr);
    fused2_kernel<<<NB * (NT / TTILE), 256, 0, stream>>>(x, W1, b1, W2, b2, afr, out);
}